// Round 4
// baseline (464.262 us; speedup 1.0000x reference)
//
#include <hip/hip_runtime.h>

// Nearest-qpoint quantize, bit-exact vs numpy reference:
//   j = #{k : q[k] < x}  (== searchsorted(q, x, 'left'))
//   lo = q[clip(j-1,0,15)]; hi = q[clip(j,0,15)]
//   out = |x-lo| <= |x-hi| ? lo : hi        (fp32 subs, ties -> lo)
//
// R2: fused chain — one v_cmp per qpoint drives BOTH lo and hi cndmasks
// (conditions are complementary), ~51 VALU ops/elem vs ~68. Exact-division
// fast path: 8192 blocks x 256 thr x 8 float4, all 8 loads issued before
// compute (MLP), nontemporal load/store (pure stream, skip L2 alloc).
// R3: __builtin_nontemporal_* requires a NATIVE vector type, not HIP's
// struct float4 -> use ext_vector_type(4).

typedef float vfloat4 __attribute__((ext_vector_type(4)));

__device__ __forceinline__ float quant1(float xv, const float qp[16]) {
    // cond_k = (qp[k] < xv). lo = last qp[k] with cond (else qp[0]);
    // hi = element AFTER the last cond (else qp[0]); k=15 cond -> hi=qp[15].
    bool c0 = qp[0] < xv;
    float lo = qp[0];
    float hi = c0 ? qp[1] : qp[0];
#pragma unroll
    for (int k = 1; k <= 14; ++k) {
        bool c = qp[k] < xv;
        lo = c ? qp[k] : lo;
        hi = c ? qp[k + 1] : hi;
    }
    bool c15 = qp[15] < xv;
    lo = c15 ? qp[15] : lo;
    hi = c15 ? qp[15] : hi;
    return (fabsf(xv - lo) <= fabsf(xv - hi)) ? lo : hi;
}

__device__ __forceinline__ vfloat4 quant4(vfloat4 v, const float qp[16]) {
    vfloat4 r;
    r.x = quant1(v.x, qp);
    r.y = quant1(v.y, qp);
    r.z = quant1(v.z, qp);
    r.w = quant1(v.w, qp);
    return r;
}

__device__ __forceinline__ void load_qp(const float* __restrict__ q,
                                        float qp[16]) {
    const vfloat4* q4 = (const vfloat4*)q;
    vfloat4 q0 = q4[0], q1 = q4[1], q2 = q4[2], q3 = q4[3];
    qp[0] = q0.x; qp[1] = q0.y; qp[2] = q0.z; qp[3] = q0.w;
    qp[4] = q1.x; qp[5] = q1.y; qp[6] = q1.z; qp[7] = q1.w;
    qp[8] = q2.x; qp[9] = q2.y; qp[10] = q2.z; qp[11] = q2.w;
    qp[12] = q3.x; qp[13] = q3.y; qp[14] = q3.z; qp[15] = q3.w;
}

// Fast path: n4 == gridDim.x * 256 * 8 exactly. No bounds checks.
__global__ __launch_bounds__(256) void qquant_x8(
    const vfloat4* __restrict__ x, const float* __restrict__ q,
    vfloat4* __restrict__ out) {
    float qp[16];
    load_qp(q, qp);

    int stride = gridDim.x * 256;
    int base = blockIdx.x * 256 + threadIdx.x;

    vfloat4 v[8];
#pragma unroll
    for (int u = 0; u < 8; ++u)
        v[u] = __builtin_nontemporal_load(&x[base + u * stride]);
#pragma unroll
    for (int u = 0; u < 8; ++u) {
        vfloat4 r = quant4(v[u], qp);
        __builtin_nontemporal_store(r, &out[base + u * stride]);
    }
}

// Generic fallback: grid-stride over float4s.
__global__ __launch_bounds__(256) void qquant_vec4(
    const vfloat4* __restrict__ x, const float* __restrict__ q,
    vfloat4* __restrict__ out, int n4) {
    float qp[16];
    load_qp(q, qp);
    int stride = gridDim.x * blockDim.x;
    for (int i = blockIdx.x * blockDim.x + threadIdx.x; i < n4; i += stride) {
        vfloat4 r = quant4(x[i], qp);
        out[i] = r;
    }
}

__global__ void qquant_tail(const float* __restrict__ x,
                            const float* __restrict__ q,
                            float* __restrict__ out, int start, int n) {
    int i = start + threadIdx.x;
    if (i >= n) return;
    float qp[16];
    load_qp(q, qp);
    out[i] = quant1(x[i], qp);
}

extern "C" void kernel_launch(void* const* d_in, const int* in_sizes, int n_in,
                              void* d_out, int out_size, void* d_ws, size_t ws_size,
                              hipStream_t stream) {
    const float* x = (const float*)d_in[0];
    const float* q = (const float*)d_in[1];
    float* out = (float*)d_out;
    int n = in_sizes[0];

    int n4 = n >> 2;
    const int ELEMS_PER_BLOCK = 256 * 8;  // 2048 float4s
    if (n4 > 0) {
        if (n4 % ELEMS_PER_BLOCK == 0) {
            // 67108864 elems -> n4=16777216 -> 8192 blocks exactly.
            int blocks = n4 / ELEMS_PER_BLOCK;
            qquant_x8<<<blocks, 256, 0, stream>>>((const vfloat4*)x, q,
                                                  (vfloat4*)out);
        } else {
            int blocks = (n4 + 255) / 256;
            if (blocks > 8192) blocks = 8192;
            qquant_vec4<<<blocks, 256, 0, stream>>>((const vfloat4*)x, q,
                                                    (vfloat4*)out, n4);
        }
    }
    int rem = n & 3;
    if (rem > 0) {
        qquant_tail<<<1, 64, 0, stream>>>(x, q, out, n4 << 2, n);
    }
}